// Round 13
// baseline (50.599 us; speedup 1.0000x reference)
//
#include <hip/hip_runtime.h>
#include <math.h>

#define N_WIRES 12

__host__ __device__ constexpr int parity12(int x) {
  x ^= x >> 8; x ^= x >> 4; x ^= x >> 2; x ^= x >> 1;
  return x & 1;
}

// physical lane mapping of storage bits (vqc):
//   s9->l0, s8->l1, s7->l2, s6->l3, s5->l4, s11->l5 ; s10 -> WAVE bit.
__host__ __device__ constexpr int lanemask_of(int m) {
  return (((m >> 9) & 1) << 0) | (((m >> 8) & 1) << 1) |
         (((m >> 7) & 1) << 2) | (((m >> 6) & 1) << 3) |
         (((m >> 5) & 1) << 4) | (((m >> 11) & 1) << 5);
}

typedef float2 f2;
__device__ __forceinline__ f2 mk2(float a, float b) { f2 r; r.x = a; r.y = b; return r; }
__device__ __forceinline__ f2 pkmul(f2 a, f2 b) {
  f2 d; asm("v_pk_mul_f32 %0, %1, %2" : "=v"(d) : "v"(a), "v"(b)); return d;
}
__device__ __forceinline__ f2 pkfma(f2 a, f2 b, f2 c) {
  f2 d; asm("v_pk_fma_f32 %0, %1, %2, %3" : "=v"(d) : "v"(a), "v"(b), "v"(c)); return d;
}
__device__ __forceinline__ f2 swap2(f2 v) { return mk2(v.y, v.x); }

struct cpx { float r, i; };
__device__ __forceinline__ cpx cmulc(cpx a, cpx b) {
  return {a.r * b.r - a.i * b.i, a.r * b.i + a.i * b.r};
}
__device__ __forceinline__ cpx fpick(float r0, float i0, float r1, float i1, int b) {
  cpx c; c.r = b ? r1 : r0; c.i = b ? i1 : i0; return c;
}
__device__ __forceinline__ float rl(float v, int l) {
  return __int_as_float(__builtin_amdgcn_readlane(__float_as_int(v), l));
}

template <int CTRL>
__device__ __forceinline__ float dppmov(float v) {
  return __int_as_float(
      __builtin_amdgcn_mov_dpp(__float_as_int(v), CTRL, 0xF, 0xF, true));
}

// lane-xor: DPP for nibble masks (all compositions HW-verified by R9/R10),
// __shfl_xor (DS) for bits 4/5.  NO raw permlane asm.
template <int LM>
__device__ __forceinline__ float lshfl(float v) {
  if constexpr (LM == 0) {
    return v;
  } else if constexpr (LM == 0x01) {
    return dppmov<0xB1>(v);
  } else if constexpr (LM == 0x02) {
    return dppmov<0x4E>(v);
  } else if constexpr (LM == 0x03) {
    return dppmov<0x1B>(v);
  } else if constexpr (LM == 0x04) {
    return dppmov<0x1B>(dppmov<0x141>(v));   // xor7 ^ xor3 = xor4
  } else if constexpr (LM == 0x07) {
    return dppmov<0x141>(v);                 // row_half_mirror = xor7
  } else if constexpr (LM == 0x08) {
    return dppmov<0x141>(dppmov<0x140>(v));  // xorF ^ xor7 = xor8
  } else if constexpr (LM == 0x0F) {
    return dppmov<0x140>(v);                 // row_mirror = xorF
  } else if constexpr ((LM & 0x30) != 0) {
    return lshfl<LM & 0x0F>(__shfl_xor(v, LM & 0x30, 64));
  } else {
    return __shfl_xor(v, LM, 64);
  }
}
template <int LM>
__device__ __forceinline__ f2 lshfl2(f2 v) {
  return mk2(lshfl<LM>(v.x), lshfl<LM>(v.y));
}

// ---------------------------------------------------------------------------
// Kernel 1: fold the two TT cores into W, padded layout (unchanged).
//   Wt[k*96 + og*12 + j],  o = og*9+j
// ---------------------------------------------------------------------------
__global__ __launch_bounds__(256) void build_w_kernel(
    const float* __restrict__ core0,   // (1,32,8,16)
    const float* __restrict__ core1,   // (16,32,9,1)
    float* __restrict__ Wt) {          // (1024,96) padded
  int idx = blockIdx.x * 256 + threadIdx.x;
  int k = idx / 72;
  int o = idx - k * 72;
  int i = k >> 5, jj = k & 31;
  int p = o / 9, r = o - p * 9;
  float acc = 0.f;
#pragma unroll
  for (int q = 0; q < 16; ++q) {
    acc += core0[(i * 8 + p) * 16 + q] * core1[(q * 32 + jj) * 9 + r];
  }
  int og = o / 9, j = o - og * 9;
  Wt[k * 96 + og * 12 + j] = acc;
}

// ---------------------------------------------------------------------------
// Kernel 2: tt GEMM v4 (unchanged from R10/R11, passing).
// ---------------------------------------------------------------------------
__global__ __launch_bounds__(512, 2) void tt_gemm4(
    const float* __restrict__ x,       // (2048,1024)
    const float* __restrict__ Wt,      // (1024,96) padded
    const float* __restrict__ bias,    // (72,)
    float* __restrict__ ttout) {       // (2048,72)
  __shared__ __align__(16) float ws[128 * 100];
  __shared__ __align__(16) float xs[8 * 132];
  const int t = threadIdx.x;
  const int lane = t & 63;
  const int og = t >> 6;
  const int kk = lane & 15;
  const int rq = lane >> 4;
  const int row0 = blockIdx.x * 8;

  float a0[9], a1[9];
#pragma unroll
  for (int j = 0; j < 9; ++j) { a0[j] = 0.f; a1[j] = 0.f; }

  for (int s = 0; s < 8; ++s) {
    __syncthreads();
    const float4* Wg = (const float4*)(Wt + (size_t)s * 128 * 96);
#pragma unroll
    for (int i = 0; i < 6; ++i) {
      const int idx = i * 512 + t;
      const int r = idx / 24, c = idx - r * 24;
      *(float4*)&ws[r * 100 + c * 4] = Wg[idx];
    }
    if (t < 256) {
      const int rr = t >> 5, j4 = t & 31;
      *(float4*)&xs[rr * 132 + j4 * 4] =
          *(const float4*)(x + (size_t)(row0 + rr) * 1024 + s * 128 + j4 * 4);
    }
    __syncthreads();
#pragma unroll
    for (int i = 0; i < 8; ++i) {
      const int k = kk + i * 16;
      const float4 wA = *(const float4*)&ws[k * 100 + og * 12];
      const float4 wB = *(const float4*)&ws[k * 100 + og * 12 + 4];
      const float w8 = ws[k * 100 + og * 12 + 8];
      const float x0v = xs[(rq * 2) * 132 + k];
      const float x1v = xs[(rq * 2 + 1) * 132 + k];
      a0[0] += x0v * wA.x; a0[1] += x0v * wA.y;
      a0[2] += x0v * wA.z; a0[3] += x0v * wA.w;
      a0[4] += x0v * wB.x; a0[5] += x0v * wB.y;
      a0[6] += x0v * wB.z; a0[7] += x0v * wB.w;
      a0[8] += x0v * w8;
      a1[0] += x1v * wA.x; a1[1] += x1v * wA.y;
      a1[2] += x1v * wA.z; a1[3] += x1v * wA.w;
      a1[4] += x1v * wB.x; a1[5] += x1v * wB.y;
      a1[6] += x1v * wB.z; a1[7] += x1v * wB.w;
      a1[8] += x1v * w8;
    }
  }

#pragma unroll
  for (int j = 0; j < 9; ++j) {
    a0[j] += lshfl<0x01>(a0[j]);
    a0[j] += lshfl<0x02>(a0[j]);
    a0[j] += lshfl<0x04>(a0[j]);
    a0[j] += lshfl<0x08>(a0[j]);
    a1[j] += lshfl<0x01>(a1[j]);
    a1[j] += lshfl<0x02>(a1[j]);
    a1[j] += lshfl<0x04>(a1[j]);
    a1[j] += lshfl<0x08>(a1[j]);
  }
  if (kk == 0) {
#pragma unroll
    for (int j = 0; j < 9; ++j) {
      const float bj = bias[og * 9 + j];
      ttout[(size_t)(row0 + rq * 2) * 72 + og * 9 + j] = a0[j] + bj;
      ttout[(size_t)(row0 + rq * 2 + 1) * 72 + og * 9 + j] = a1[j] + bj;
    }
  }
}

// ---------------------------------------------------------------------------
// Packed single-qubit gate; 2-wave-per-row state, 16 packs (32 amps)/thread.
//   (byte-identical to R9/R10's passing gate9)
// ---------------------------------------------------------------------------
template <int MASK, int ROW>
__device__ __forceinline__ void gate9(f2 R[16], f2 I[16],
    float u00r, float u00i, float u01r, float u01i,
    f2* __restrict__ buf, int t, int lane, int wq) {
  constexpr int RM   = MASK & 0x1F;
  constexpr int LMP  = lanemask_of(MASK);
  constexpr int WB   = (MASK >> 10) & 1;
  constexpr int ROWL = lanemask_of(ROW);
  constexpr int RWB  = (ROW >> 10) & 1;
  constexpr int FLIP = parity12(ROW & 3);
  constexpr int JX = (RM == 0) ? 0 : (((RM & 1) ? (RM ^ 3) : RM) >> 1);
  constexpr bool SW = (RM & 1) != 0;

  const int tsgn = ((__popc(ROWL & lane) ^ (RWB & wq)) & 1) << 31;
  const float dEi = __int_as_float(__float_as_int(u00i) ^ tsgn);
  const float oEr = __int_as_float(__float_as_int(u01r) ^ tsgn);
  const float ndEi = -dEi, noEr = -oEr;
  const f2 A  = mk2(u00r, u00r);
  const f2 C  = mk2(u01i, u01i);
  const f2 nC = mk2(-u01i, -u01i);

  auto Dof = [&](int pe, int ph) { return mk2(pe ? ndEi : dEi, ph ? ndEi : dEi); };
  auto Oof = [&](int pe, int ph) { return mk2(pe ? noEr : oEr, ph ? noEr : oEr); };

  auto upd = [&](int j, f2 Rb, f2 Ib, f2& outR, f2& outI) {
    const int pe = parity12(ROW & (2 * j));
    const int ph = pe ^ FLIP;
    const f2 Dj = Dof(pe, ph), nDj = Dof(!pe, !ph), Oj = Oof(pe, ph);
    const f2 a = R[j], ii = I[j];
    outR = pkfma(A, a, pkfma(nDj, ii, pkfma(Oj, Rb, pkmul(nC, Ib))));
    outI = pkfma(Dj, a, pkfma(A, ii, pkfma(C, Rb, pkmul(Oj, Ib))));
  };

  if constexpr (WB) {
    static_assert(RM == 0, "wave-crossing gate must have no reg part");
    const int tp = t ^ 64 ^ LMP;            // flip wave bit (+ lane part)
#pragma unroll
    for (int ph2 = 0; ph2 < 2; ++ph2) {
      __syncthreads();
#pragma unroll
      for (int j = 0; j < 8; ++j) {
        buf[(j * 2 + 0) * 256 + t] = R[ph2 * 8 + j];
        buf[(j * 2 + 1) * 256 + t] = I[ph2 * 8 + j];
      }
      __syncthreads();
#pragma unroll
      for (int j = 0; j < 8; ++j) {
        const f2 Rb = buf[(j * 2 + 0) * 256 + tp];
        const f2 Ib = buf[(j * 2 + 1) * 256 + tp];
        upd(ph2 * 8 + j, Rb, Ib, R[ph2 * 8 + j], I[ph2 * 8 + j]);
      }
    }
  } else if constexpr (LMP != 0 && RM == 0) {
#pragma unroll
    for (int j = 0; j < 16; ++j) {
      const f2 Rb = lshfl2<LMP>(R[j]);
      const f2 Ib = lshfl2<LMP>(I[j]);
      f2 nR, nI;
      upd(j, Rb, Ib, nR, nI);
      R[j] = nR; I[j] = nI;
    }
  } else if constexpr (LMP != 0 && RM != 0) {
#pragma unroll
    for (int j = 0; j < 16; ++j) {
      const int j2 = j ^ JX;
      if (j < j2) {
        f2 Rb1 = lshfl2<LMP>(R[j2]), Ib1 = lshfl2<LMP>(I[j2]);
        f2 Rb2 = lshfl2<LMP>(R[j]),  Ib2 = lshfl2<LMP>(I[j]);
        if constexpr (SW) {
          Rb1 = swap2(Rb1); Ib1 = swap2(Ib1);
          Rb2 = swap2(Rb2); Ib2 = swap2(Ib2);
        }
        f2 nR1, nI1, nR2, nI2;
        upd(j, Rb1, Ib1, nR1, nI1);
        upd(j2, Rb2, Ib2, nR2, nI2);
        R[j] = nR1; I[j] = nI1; R[j2] = nR2; I[j2] = nI2;
      }
    }
  } else {
#pragma unroll
    for (int j = 0; j < 16; ++j) {
      const int j2 = j ^ JX;
      if (j < j2) {
        f2 Rb1 = R[j2], Ib1 = I[j2], Rb2 = R[j], Ib2 = I[j];
        if constexpr (SW) {
          Rb1 = swap2(Rb1); Ib1 = swap2(Ib1);
          Rb2 = swap2(Rb2); Ib2 = swap2(Ib2);
        }
        f2 nR1, nI1, nR2, nI2;
        upd(j, Rb1, Ib1, nR1, nI1);
        upd(j2, Rb2, Ib2, nR2, nI2);
        R[j] = nR1; I[j] = nI1; R[j2] = nR2; I[j2] = nI2;
      }
    }
  }
}

// ---------------------------------------------------------------------------
// Kernel 3: statevector sim, TWO waves per batch row, 32 amps/thread.
// Byte-identical to R10's passing vqc_kernel10 EXCEPT __launch_bounds__
// (256,3) -> (256,4): VGPR cap 128 -> 4 waves/SIMD (16 waves/CU), the one
// occupancy point never tested.  Single-variable experiment.
// ---------------------------------------------------------------------------
__global__ __launch_bounds__(256, 4) void vqc_kernel10(
    const float* __restrict__ x,        // (2048,1024) -- only first 12 cols used
    const float* __restrict__ ttout,    // (2048,72)
    const float* __restrict__ gang,     // (2,12,3)
    float* __restrict__ out) {          // (2048,12)
  const int t = threadIdx.x;
  const int lane = t & 63;
  const int wq = (t >> 6) & 1;               // wave within row = s10
  const int row = t >> 7;                    // row within block
  const int b = blockIdx.x * 2 + row;
  const float* ttb = ttout + (size_t)b * 72;

  __shared__ __align__(16) f2 buf[4096];     // 32 KiB exchange / reduce

  float c0 = 0.f, c1 = 0.f, c2 = 0.f, c3 = 0.f;
  const bool uLane = lane < 12;
  const bool fLane = (lane >= 16) && (lane < 28);
  if (uLane || fLane) {
    const int w = uLane ? lane : lane - 16;
    const int k = uLane ? 1 : 0;
    const int gbase = (k * 12 + w) * 3;
    const int tbase = k * 36 + w * 3;
    const float a0 = gang[gbase + 0] + ttb[tbase + 0];
    const float a1 = gang[gbase + 1] + ttb[tbase + 1];
    const float a2 = gang[gbase + 2] + ttb[tbase + 2];
    const float cx = cosf(0.5f * a0), sx = sinf(0.5f * a0);
    const float cy = cosf(0.5f * a1), sy = sinf(0.5f * a1);
    const float cz = cosf(0.5f * a2), sz = sinf(0.5f * a2);
    const float m00r = cy * cx,   m00i = sy * sx;
    const float m01r = -sy * cx,  m01i = -cy * sx;
    const float m10r = sy * cx,   m10i = -cy * sx;
    const float m11r = cy * cx,   m11i = -sy * sx;
    const float U00r = cz * m00r + sz * m00i, U00i = cz * m00i - sz * m00r;
    const float U01r = cz * m01r + sz * m01i, U01i = cz * m01i - sz * m01r;
    const float U10r = cz * m10r - sz * m10i, U10i = cz * m10i + sz * m10r;
    const float U11r = cz * m11r - sz * m11i, U11i = cz * m11i + sz * m11r;
    if (uLane) {
      c0 = U00r; c1 = U00i; c2 = U01r; c3 = U01i;
    } else {
      const float e = x[(size_t)b * 1024 + w] * 0.5f;
      const float cc = cosf(e), ss = sinf(e);
      c0 = U00r * cc + U01r * ss;  c1 = U00i * cc + U01i * ss;
      c2 = U10r * cc + U11r * ss;  c3 = U10i * cc + U11i * ss;
    }
  }

  const int bw0 = (lane >> 5) & 1;                   // w0 = l5
  const int bw1 = (wq ^ lane) & 1;                   // w1 = wq^l0
  const int bw2 = (lane ^ (lane >> 1)) & 1;          // w2 = l0^l1
  const int bw3 = ((lane >> 1) ^ (lane >> 2)) & 1;   // w3 = l1^l2
  const int bw4 = ((lane >> 2) ^ (lane >> 3)) & 1;   // w4 = l2^l3
  const int bw5 = ((lane >> 3) ^ (lane >> 4)) & 1;   // w5 = l3^l4
  const int l4 = (lane >> 4) & 1;                    // w6 = l4^r4

  cpx P = fpick(rl(c0, 16), rl(c1, 16), rl(c2, 16), rl(c3, 16), bw0);
  P = cmulc(P, fpick(rl(c0, 17), rl(c1, 17), rl(c2, 17), rl(c3, 17), bw1));
  P = cmulc(P, fpick(rl(c0, 18), rl(c1, 18), rl(c2, 18), rl(c3, 18), bw2));
  P = cmulc(P, fpick(rl(c0, 19), rl(c1, 19), rl(c2, 19), rl(c3, 19), bw3));
  P = cmulc(P, fpick(rl(c0, 20), rl(c1, 20), rl(c2, 20), rl(c3, 20), bw4));
  P = cmulc(P, fpick(rl(c0, 21), rl(c1, 21), rl(c2, 21), rl(c3, 21), bw5));

  cpx PT[8];
  {
    const cpx F6a = fpick(rl(c0, 22), rl(c1, 22), rl(c2, 22), rl(c3, 22), l4);
    const cpx F6b = fpick(rl(c0, 22), rl(c1, 22), rl(c2, 22), rl(c3, 22), l4 ^ 1);
    cpx F7[2], F8[2];
    F7[0] = {rl(c0, 23), rl(c1, 23)};  F7[1] = {rl(c2, 23), rl(c3, 23)};
    F8[0] = {rl(c0, 24), rl(c1, 24)};  F8[1] = {rl(c2, 24), rl(c3, 24)};
    const cpx P6a = cmulc(P, F6a), P6b = cmulc(P, F6b);
    cpx t67[4];
#pragma unroll
    for (int i = 0; i < 4; ++i) {
      const int r4 = i >> 1, r3 = i & 1;
      t67[i] = cmulc(r4 ? P6b : P6a, F7[r4 ^ r3]);
    }
#pragma unroll
    for (int i = 0; i < 8; ++i) {
      const int r3 = (i >> 1) & 1, r2 = i & 1;
      PT[i] = cmulc(t67[i >> 1], F8[r3 ^ r2]);
    }
  }

  cpx TLo[8];
  {
    cpx F9[2], F10[2], F11[2];
    F9[0]  = {rl(c0, 25), rl(c1, 25)};  F9[1]  = {rl(c2, 25), rl(c3, 25)};
    F10[0] = {rl(c0, 26), rl(c1, 26)};  F10[1] = {rl(c2, 26), rl(c3, 26)};
    F11[0] = {rl(c0, 27), rl(c1, 27)};  F11[1] = {rl(c2, 27), rl(c3, 27)};
    cpx t01[4];
#pragma unroll
    for (int i = 0; i < 4; ++i) {
      const int r1 = i >> 1, r0 = i & 1;
      t01[i] = cmulc(F10[r1 ^ r0], F11[r0]);
    }
#pragma unroll
    for (int i = 0; i < 8; ++i) {
      const int r2 = i >> 2, r1 = (i >> 1) & 1;
      TLo[i] = cmulc(F9[r2 ^ r1], t01[i & 3]);
    }
  }

  f2 R[16], I[16];
#pragma unroll
  for (int j = 0; j < 16; ++j) {
    const cpx Av = PT[j >> 1];
    const int il = (2 * j) & 7;
    const f2 Tre = mk2(TLo[il].r, TLo[il ^ 3].r);
    const f2 Tim = mk2(TLo[il].i, TLo[il ^ 3].i);
    const f2 Ar = mk2(Av.r, Av.r);
    R[j] = pkfma(mk2(-Av.i, -Av.i), Tim, pkmul(Ar, Tre));
    I[j] = pkfma(mk2(Av.i, Av.i), Tre, pkmul(Ar, Tim));
  }

#define GATE(MASK, ROW, G)                                                  \
  gate9<MASK, ROW>(R, I, rl(c0, G), rl(c1, G), rl(c2, G), rl(c3, G),        \
                   buf, t, lane, wq)

  GATE(0xC00, 0x400, 0);    // w=0   WAVE + l5        (LDS exchange)
  GATE(0x200, 0xE00, 1);    // w=1   lane 0x01        (DPP)
  GATE(0x100, 0xD00, 2);    // w=2   lane 0x02        (DPP)
  GATE(0x080, 0xC80, 3);    // w=3   lane 0x04        (DPP x2)
  GATE(0x040, 0xC40, 4);    // w=4   lane 0x08        (DPP x2)
  GATE(0x020, 0xC20, 5);    // w=5   lane 0x10        (shfl)
  GATE(0x010, 0xC10, 6);    // w=6   reg 0x10
  GATE(0x008, 0xC08, 7);    // w=7   reg 8
  GATE(0x004, 0xC04, 8);    // w=8   reg 4
  GATE(0x002, 0xC02, 9);    // w=9   reg 2
  GATE(0x001, 0xC01, 10);   // w=10  reg 1 (half-swap)
  GATE(0xBFF, 0xC00, 11);   // w=11  lane 0x3F (shfl 0x30 + mirror) + reg 0x1F
#undef GATE

  constexpr int MROWS[12] = {0xFFF, 0xA00, 0x700, 0xB80, 0x7C0, 0xBE0,
                             0x7F0, 0xBF8, 0x7FC, 0xBFE, 0x7FF, 0xBFF};
  const f2 Spp = mk2(1.f, 1.f),  Smm = mk2(-1.f, -1.f);
  const f2 Spm = mk2(1.f, -1.f), Smp = mk2(-1.f, 1.f);
  f2 acc2[12];
#pragma unroll
  for (int w = 0; w < 12; ++w) acc2[w] = mk2(0.f, 0.f);
#pragma unroll
  for (int j = 0; j < 16; ++j) {
    const f2 pr2 = pkfma(I[j], I[j], pkmul(R[j], R[j]));
#pragma unroll
    for (int w = 0; w < 12; ++w) {
      const int sl = parity12(MROWS[w] & (2 * j));
      const int sh = sl ^ parity12(MROWS[w] & 3);
      const f2 S = sl ? (sh ? Smm : Smp) : (sh ? Spm : Spp);
      acc2[w] = pkfma(S, pr2, acc2[w]);
    }
  }
  __syncthreads();                           // gate-0 buf reads long done
  float* sred = (float*)buf;
#pragma unroll
  for (int w = 0; w < 12; ++w) {
    float v = acc2[w].x + acc2[w].y;
    const int sg = (__popc(lanemask_of(MROWS[w]) & lane) ^
                    (wq & ((MROWS[w] >> 10) & 1))) & 1;
    if (sg) v = -v;
    v += lshfl<0x01>(v);
    v += lshfl<0x02>(v);
    v += lshfl<0x04>(v);
    v += lshfl<0x08>(v);
    v += __shfl_xor(v, 16, 64);
    v += __shfl_xor(v, 32, 64);
    if (lane == 0) sred[(t >> 6) * 12 + w] = v;
  }
  __syncthreads();
  if (t < 24) {
    const int rr = t / 12, w = t - rr * 12;
    out[(size_t)(blockIdx.x * 2 + rr) * 12 + w] =
        sred[(rr * 2) * 12 + w] + sred[(rr * 2 + 1) * 12 + w];
  }
}

// ---------------------------------------------------------------------------
extern "C" void kernel_launch(void* const* d_in, const int* in_sizes, int n_in,
                              void* d_out, int out_size, void* d_ws, size_t ws_size,
                              hipStream_t stream) {
  const float* x       = (const float*)d_in[0];
  const float* core0   = (const float*)d_in[1];
  const float* core1   = (const float*)d_in[2];
  const float* tt_bias = (const float*)d_in[3];
  const float* gang    = (const float*)d_in[4];
  float* out = (float*)d_out;
  float* Wt     = (float*)d_ws;                 // 1024*96 floats = 384 KiB
  float* ttout  = (float*)d_ws + 98304;         // 2048*72 floats = 576 KiB

  const int bsz = in_sizes[0] / 1024;  // 2048

  build_w_kernel<<<288, 256, 0, stream>>>(core0, core1, Wt);
  tt_gemm4<<<bsz / 8, 512, 0, stream>>>(x, Wt, tt_bias, ttout);
  vqc_kernel10<<<bsz / 2, 256, 0, stream>>>(x, ttout, gang, out);
}

// Round 14
// 49.748 us; speedup vs baseline: 1.0171x; 1.0171x over previous
//
#include <hip/hip_runtime.h>
#include <math.h>

#define N_WIRES 12

__host__ __device__ constexpr int parity12(int x) {
  x ^= x >> 8; x ^= x >> 4; x ^= x >> 2; x ^= x >> 1;
  return x & 1;
}

// physical lane mapping of storage bits (vqc):
//   s9->l0, s8->l1, s7->l2, s6->l3, s5->l4, s11->l5 ; s10 -> WAVE bit.
__host__ __device__ constexpr int lanemask_of(int m) {
  return (((m >> 9) & 1) << 0) | (((m >> 8) & 1) << 1) |
         (((m >> 7) & 1) << 2) | (((m >> 6) & 1) << 3) |
         (((m >> 5) & 1) << 4) | (((m >> 11) & 1) << 5);
}

typedef float2 f2;
__device__ __forceinline__ f2 mk2(float a, float b) { f2 r; r.x = a; r.y = b; return r; }
__device__ __forceinline__ f2 pkmul(f2 a, f2 b) {
  f2 d; asm("v_pk_mul_f32 %0, %1, %2" : "=v"(d) : "v"(a), "v"(b)); return d;
}
__device__ __forceinline__ f2 pkfma(f2 a, f2 b, f2 c) {
  f2 d; asm("v_pk_fma_f32 %0, %1, %2, %3" : "=v"(d) : "v"(a), "v"(b), "v"(c)); return d;
}
__device__ __forceinline__ f2 swap2(f2 v) { return mk2(v.y, v.x); }

struct cpx { float r, i; };
__device__ __forceinline__ cpx cmulc(cpx a, cpx b) {
  return {a.r * b.r - a.i * b.i, a.r * b.i + a.i * b.r};
}
__device__ __forceinline__ cpx fpick(float r0, float i0, float r1, float i1, int b) {
  cpx c; c.r = b ? r1 : r0; c.i = b ? i1 : i0; return c;
}
__device__ __forceinline__ float rl(float v, int l) {
  return __int_as_float(__builtin_amdgcn_readlane(__float_as_int(v), l));
}

template <int CTRL>
__device__ __forceinline__ float dppmov(float v) {
  return __int_as_float(
      __builtin_amdgcn_mov_dpp(__float_as_int(v), CTRL, 0xF, 0xF, true));
}

// lane-xor: DPP for nibble masks (all compositions HW-verified by R9/R10),
// __shfl_xor (DS) for bits 4/5.  NO raw permlane asm.
template <int LM>
__device__ __forceinline__ float lshfl(float v) {
  if constexpr (LM == 0) {
    return v;
  } else if constexpr (LM == 0x01) {
    return dppmov<0xB1>(v);
  } else if constexpr (LM == 0x02) {
    return dppmov<0x4E>(v);
  } else if constexpr (LM == 0x03) {
    return dppmov<0x1B>(v);
  } else if constexpr (LM == 0x04) {
    return dppmov<0x1B>(dppmov<0x141>(v));   // xor7 ^ xor3 = xor4
  } else if constexpr (LM == 0x07) {
    return dppmov<0x141>(v);                 // row_half_mirror = xor7
  } else if constexpr (LM == 0x08) {
    return dppmov<0x141>(dppmov<0x140>(v));  // xorF ^ xor7 = xor8
  } else if constexpr (LM == 0x0F) {
    return dppmov<0x140>(v);                 // row_mirror = xorF
  } else if constexpr ((LM & 0x30) != 0) {
    return lshfl<LM & 0x0F>(__shfl_xor(v, LM & 0x30, 64));
  } else {
    return __shfl_xor(v, LM, 64);
  }
}
template <int LM>
__device__ __forceinline__ f2 lshfl2(f2 v) {
  return mk2(lshfl<LM>(v.x), lshfl<LM>(v.y));
}

// ---------------------------------------------------------------------------
// Kernel 1: fold the two TT cores into W, padded layout (unchanged).
//   Wt[k*96 + og*12 + j],  o = og*9+j
// ---------------------------------------------------------------------------
__global__ __launch_bounds__(256) void build_w_kernel(
    const float* __restrict__ core0,   // (1,32,8,16)
    const float* __restrict__ core1,   // (16,32,9,1)
    float* __restrict__ Wt) {          // (1024,96) padded
  int idx = blockIdx.x * 256 + threadIdx.x;
  int k = idx / 72;
  int o = idx - k * 72;
  int i = k >> 5, jj = k & 31;
  int p = o / 9, r = o - p * 9;
  float acc = 0.f;
#pragma unroll
  for (int q = 0; q < 16; ++q) {
    acc += core0[(i * 8 + p) * 16 + q] * core1[(q * 32 + jj) * 9 + r];
  }
  int og = o / 9, j = o - og * 9;
  Wt[k * 96 + og * 12 + j] = acc;
}

// ---------------------------------------------------------------------------
// Kernel 2: tt GEMM v4 (unchanged from R10..R13, passing).
// ---------------------------------------------------------------------------
__global__ __launch_bounds__(512, 2) void tt_gemm4(
    const float* __restrict__ x,       // (2048,1024)
    const float* __restrict__ Wt,      // (1024,96) padded
    const float* __restrict__ bias,    // (72,)
    float* __restrict__ ttout) {       // (2048,72)
  __shared__ __align__(16) float ws[128 * 100];
  __shared__ __align__(16) float xs[8 * 132];
  const int t = threadIdx.x;
  const int lane = t & 63;
  const int og = t >> 6;
  const int kk = lane & 15;
  const int rq = lane >> 4;
  const int row0 = blockIdx.x * 8;

  float a0[9], a1[9];
#pragma unroll
  for (int j = 0; j < 9; ++j) { a0[j] = 0.f; a1[j] = 0.f; }

  for (int s = 0; s < 8; ++s) {
    __syncthreads();
    const float4* Wg = (const float4*)(Wt + (size_t)s * 128 * 96);
#pragma unroll
    for (int i = 0; i < 6; ++i) {
      const int idx = i * 512 + t;
      const int r = idx / 24, c = idx - r * 24;
      *(float4*)&ws[r * 100 + c * 4] = Wg[idx];
    }
    if (t < 256) {
      const int rr = t >> 5, j4 = t & 31;
      *(float4*)&xs[rr * 132 + j4 * 4] =
          *(const float4*)(x + (size_t)(row0 + rr) * 1024 + s * 128 + j4 * 4);
    }
    __syncthreads();
#pragma unroll
    for (int i = 0; i < 8; ++i) {
      const int k = kk + i * 16;
      const float4 wA = *(const float4*)&ws[k * 100 + og * 12];
      const float4 wB = *(const float4*)&ws[k * 100 + og * 12 + 4];
      const float w8 = ws[k * 100 + og * 12 + 8];
      const float x0v = xs[(rq * 2) * 132 + k];
      const float x1v = xs[(rq * 2 + 1) * 132 + k];
      a0[0] += x0v * wA.x; a0[1] += x0v * wA.y;
      a0[2] += x0v * wA.z; a0[3] += x0v * wA.w;
      a0[4] += x0v * wB.x; a0[5] += x0v * wB.y;
      a0[6] += x0v * wB.z; a0[7] += x0v * wB.w;
      a0[8] += x0v * w8;
      a1[0] += x1v * wA.x; a1[1] += x1v * wA.y;
      a1[2] += x1v * wA.z; a1[3] += x1v * wA.w;
      a1[4] += x1v * wB.x; a1[5] += x1v * wB.y;
      a1[6] += x1v * wB.z; a1[7] += x1v * wB.w;
      a1[8] += x1v * w8;
    }
  }

#pragma unroll
  for (int j = 0; j < 9; ++j) {
    a0[j] += lshfl<0x01>(a0[j]);
    a0[j] += lshfl<0x02>(a0[j]);
    a0[j] += lshfl<0x04>(a0[j]);
    a0[j] += lshfl<0x08>(a0[j]);
    a1[j] += lshfl<0x01>(a1[j]);
    a1[j] += lshfl<0x02>(a1[j]);
    a1[j] += lshfl<0x04>(a1[j]);
    a1[j] += lshfl<0x08>(a1[j]);
  }
  if (kk == 0) {
#pragma unroll
    for (int j = 0; j < 9; ++j) {
      const float bj = bias[og * 9 + j];
      ttout[(size_t)(row0 + rq * 2) * 72 + og * 9 + j] = a0[j] + bj;
      ttout[(size_t)(row0 + rq * 2 + 1) * 72 + og * 9 + j] = a1[j] + bj;
    }
  }
}

// ---------------------------------------------------------------------------
// Packed single-qubit gate; 2-wave-per-row state, 16 packs (32 amps)/thread.
//   (byte-identical to R9..R13's passing gate9)
// ---------------------------------------------------------------------------
template <int MASK, int ROW>
__device__ __forceinline__ void gate9(f2 R[16], f2 I[16],
    float u00r, float u00i, float u01r, float u01i,
    f2* __restrict__ buf, int t, int lane, int wq) {
  constexpr int RM   = MASK & 0x1F;
  constexpr int LMP  = lanemask_of(MASK);
  constexpr int WB   = (MASK >> 10) & 1;
  constexpr int ROWL = lanemask_of(ROW);
  constexpr int RWB  = (ROW >> 10) & 1;
  constexpr int FLIP = parity12(ROW & 3);
  constexpr int JX = (RM == 0) ? 0 : (((RM & 1) ? (RM ^ 3) : RM) >> 1);
  constexpr bool SW = (RM & 1) != 0;

  const int tsgn = ((__popc(ROWL & lane) ^ (RWB & wq)) & 1) << 31;
  const float dEi = __int_as_float(__float_as_int(u00i) ^ tsgn);
  const float oEr = __int_as_float(__float_as_int(u01r) ^ tsgn);
  const float ndEi = -dEi, noEr = -oEr;
  const f2 A  = mk2(u00r, u00r);
  const f2 C  = mk2(u01i, u01i);
  const f2 nC = mk2(-u01i, -u01i);

  auto Dof = [&](int pe, int ph) { return mk2(pe ? ndEi : dEi, ph ? ndEi : dEi); };
  auto Oof = [&](int pe, int ph) { return mk2(pe ? noEr : oEr, ph ? noEr : oEr); };

  auto upd = [&](int j, f2 Rb, f2 Ib, f2& outR, f2& outI) {
    const int pe = parity12(ROW & (2 * j));
    const int ph = pe ^ FLIP;
    const f2 Dj = Dof(pe, ph), nDj = Dof(!pe, !ph), Oj = Oof(pe, ph);
    const f2 a = R[j], ii = I[j];
    outR = pkfma(A, a, pkfma(nDj, ii, pkfma(Oj, Rb, pkmul(nC, Ib))));
    outI = pkfma(Dj, a, pkfma(A, ii, pkfma(C, Rb, pkmul(Oj, Ib))));
  };

  if constexpr (WB) {
    static_assert(RM == 0, "wave-crossing gate must have no reg part");
    const int tp = t ^ 64 ^ LMP;            // flip wave bit (+ lane part)
#pragma unroll
    for (int ph2 = 0; ph2 < 2; ++ph2) {
      __syncthreads();
#pragma unroll
      for (int j = 0; j < 8; ++j) {
        buf[(j * 2 + 0) * 256 + t] = R[ph2 * 8 + j];
        buf[(j * 2 + 1) * 256 + t] = I[ph2 * 8 + j];
      }
      __syncthreads();
#pragma unroll
      for (int j = 0; j < 8; ++j) {
        const f2 Rb = buf[(j * 2 + 0) * 256 + tp];
        const f2 Ib = buf[(j * 2 + 1) * 256 + tp];
        upd(ph2 * 8 + j, Rb, Ib, R[ph2 * 8 + j], I[ph2 * 8 + j]);
      }
    }
  } else if constexpr (LMP != 0 && RM == 0) {
#pragma unroll
    for (int j = 0; j < 16; ++j) {
      const f2 Rb = lshfl2<LMP>(R[j]);
      const f2 Ib = lshfl2<LMP>(I[j]);
      f2 nR, nI;
      upd(j, Rb, Ib, nR, nI);
      R[j] = nR; I[j] = nI;
    }
  } else if constexpr (LMP != 0 && RM != 0) {
#pragma unroll
    for (int j = 0; j < 16; ++j) {
      const int j2 = j ^ JX;
      if (j < j2) {
        f2 Rb1 = lshfl2<LMP>(R[j2]), Ib1 = lshfl2<LMP>(I[j2]);
        f2 Rb2 = lshfl2<LMP>(R[j]),  Ib2 = lshfl2<LMP>(I[j]);
        if constexpr (SW) {
          Rb1 = swap2(Rb1); Ib1 = swap2(Ib1);
          Rb2 = swap2(Rb2); Ib2 = swap2(Ib2);
        }
        f2 nR1, nI1, nR2, nI2;
        upd(j, Rb1, Ib1, nR1, nI1);
        upd(j2, Rb2, Ib2, nR2, nI2);
        R[j] = nR1; I[j] = nI1; R[j2] = nR2; I[j2] = nI2;
      }
    }
  } else {
#pragma unroll
    for (int j = 0; j < 16; ++j) {
      const int j2 = j ^ JX;
      if (j < j2) {
        f2 Rb1 = R[j2], Ib1 = I[j2], Rb2 = R[j], Ib2 = I[j];
        if constexpr (SW) {
          Rb1 = swap2(Rb1); Ib1 = swap2(Ib1);
          Rb2 = swap2(Rb2); Ib2 = swap2(Ib2);
        }
        f2 nR1, nI1, nR2, nI2;
        upd(j, Rb1, Ib1, nR1, nI1);
        upd(j2, Rb2, Ib2, nR2, nI2);
        R[j] = nR1; I[j] = nI1; R[j2] = nR2; I[j2] = nI2;
      }
    }
  }
}

// ---------------------------------------------------------------------------
// Kernel 3: statevector sim, TWO waves per batch row, 32 amps/thread.
// Byte-identical to R13's passing kernel EXCEPT: cosf/sinf -> __cosf/__sinf
// (HW v_cos_f32/v_sin_f32 fast path; angles bounded ~|2|, err ~1e-6,
// threshold headroom 20x).  Single-variable experiment.
// ---------------------------------------------------------------------------
__global__ __launch_bounds__(256, 4) void vqc_kernel10(
    const float* __restrict__ x,        // (2048,1024) -- only first 12 cols used
    const float* __restrict__ ttout,    // (2048,72)
    const float* __restrict__ gang,     // (2,12,3)
    float* __restrict__ out) {          // (2048,12)
  const int t = threadIdx.x;
  const int lane = t & 63;
  const int wq = (t >> 6) & 1;               // wave within row = s10
  const int row = t >> 7;                    // row within block
  const int b = blockIdx.x * 2 + row;
  const float* ttb = ttout + (size_t)b * 72;

  __shared__ __align__(16) f2 buf[4096];     // 32 KiB exchange / reduce

  float c0 = 0.f, c1 = 0.f, c2 = 0.f, c3 = 0.f;
  const bool uLane = lane < 12;
  const bool fLane = (lane >= 16) && (lane < 28);
  if (uLane || fLane) {
    const int w = uLane ? lane : lane - 16;
    const int k = uLane ? 1 : 0;
    const int gbase = (k * 12 + w) * 3;
    const int tbase = k * 36 + w * 3;
    const float a0 = gang[gbase + 0] + ttb[tbase + 0];
    const float a1 = gang[gbase + 1] + ttb[tbase + 1];
    const float a2 = gang[gbase + 2] + ttb[tbase + 2];
    const float cx = __cosf(0.5f * a0), sx = __sinf(0.5f * a0);
    const float cy = __cosf(0.5f * a1), sy = __sinf(0.5f * a1);
    const float cz = __cosf(0.5f * a2), sz = __sinf(0.5f * a2);
    const float m00r = cy * cx,   m00i = sy * sx;
    const float m01r = -sy * cx,  m01i = -cy * sx;
    const float m10r = sy * cx,   m10i = -cy * sx;
    const float m11r = cy * cx,   m11i = -sy * sx;
    const float U00r = cz * m00r + sz * m00i, U00i = cz * m00i - sz * m00r;
    const float U01r = cz * m01r + sz * m01i, U01i = cz * m01i - sz * m01r;
    const float U10r = cz * m10r - sz * m10i, U10i = cz * m10i + sz * m10r;
    const float U11r = cz * m11r - sz * m11i, U11i = cz * m11i + sz * m11r;
    if (uLane) {
      c0 = U00r; c1 = U00i; c2 = U01r; c3 = U01i;
    } else {
      const float e = x[(size_t)b * 1024 + w] * 0.5f;
      const float cc = __cosf(e), ss = __sinf(e);
      c0 = U00r * cc + U01r * ss;  c1 = U00i * cc + U01i * ss;
      c2 = U10r * cc + U11r * ss;  c3 = U10i * cc + U11i * ss;
    }
  }

  const int bw0 = (lane >> 5) & 1;                   // w0 = l5
  const int bw1 = (wq ^ lane) & 1;                   // w1 = wq^l0
  const int bw2 = (lane ^ (lane >> 1)) & 1;          // w2 = l0^l1
  const int bw3 = ((lane >> 1) ^ (lane >> 2)) & 1;   // w3 = l1^l2
  const int bw4 = ((lane >> 2) ^ (lane >> 3)) & 1;   // w4 = l2^l3
  const int bw5 = ((lane >> 3) ^ (lane >> 4)) & 1;   // w5 = l3^l4
  const int l4 = (lane >> 4) & 1;                    // w6 = l4^r4

  cpx P = fpick(rl(c0, 16), rl(c1, 16), rl(c2, 16), rl(c3, 16), bw0);
  P = cmulc(P, fpick(rl(c0, 17), rl(c1, 17), rl(c2, 17), rl(c3, 17), bw1));
  P = cmulc(P, fpick(rl(c0, 18), rl(c1, 18), rl(c2, 18), rl(c3, 18), bw2));
  P = cmulc(P, fpick(rl(c0, 19), rl(c1, 19), rl(c2, 19), rl(c3, 19), bw3));
  P = cmulc(P, fpick(rl(c0, 20), rl(c1, 20), rl(c2, 20), rl(c3, 20), bw4));
  P = cmulc(P, fpick(rl(c0, 21), rl(c1, 21), rl(c2, 21), rl(c3, 21), bw5));

  cpx PT[8];
  {
    const cpx F6a = fpick(rl(c0, 22), rl(c1, 22), rl(c2, 22), rl(c3, 22), l4);
    const cpx F6b = fpick(rl(c0, 22), rl(c1, 22), rl(c2, 22), rl(c3, 22), l4 ^ 1);
    cpx F7[2], F8[2];
    F7[0] = {rl(c0, 23), rl(c1, 23)};  F7[1] = {rl(c2, 23), rl(c3, 23)};
    F8[0] = {rl(c0, 24), rl(c1, 24)};  F8[1] = {rl(c2, 24), rl(c3, 24)};
    const cpx P6a = cmulc(P, F6a), P6b = cmulc(P, F6b);
    cpx t67[4];
#pragma unroll
    for (int i = 0; i < 4; ++i) {
      const int r4 = i >> 1, r3 = i & 1;
      t67[i] = cmulc(r4 ? P6b : P6a, F7[r4 ^ r3]);
    }
#pragma unroll
    for (int i = 0; i < 8; ++i) {
      const int r3 = (i >> 1) & 1, r2 = i & 1;
      PT[i] = cmulc(t67[i >> 1], F8[r3 ^ r2]);
    }
  }

  cpx TLo[8];
  {
    cpx F9[2], F10[2], F11[2];
    F9[0]  = {rl(c0, 25), rl(c1, 25)};  F9[1]  = {rl(c2, 25), rl(c3, 25)};
    F10[0] = {rl(c0, 26), rl(c1, 26)};  F10[1] = {rl(c2, 26), rl(c3, 26)};
    F11[0] = {rl(c0, 27), rl(c1, 27)};  F11[1] = {rl(c2, 27), rl(c3, 27)};
    cpx t01[4];
#pragma unroll
    for (int i = 0; i < 4; ++i) {
      const int r1 = i >> 1, r0 = i & 1;
      t01[i] = cmulc(F10[r1 ^ r0], F11[r0]);
    }
#pragma unroll
    for (int i = 0; i < 8; ++i) {
      const int r2 = i >> 2, r1 = (i >> 1) & 1;
      TLo[i] = cmulc(F9[r2 ^ r1], t01[i & 3]);
    }
  }

  f2 R[16], I[16];
#pragma unroll
  for (int j = 0; j < 16; ++j) {
    const cpx Av = PT[j >> 1];
    const int il = (2 * j) & 7;
    const f2 Tre = mk2(TLo[il].r, TLo[il ^ 3].r);
    const f2 Tim = mk2(TLo[il].i, TLo[il ^ 3].i);
    const f2 Ar = mk2(Av.r, Av.r);
    R[j] = pkfma(mk2(-Av.i, -Av.i), Tim, pkmul(Ar, Tre));
    I[j] = pkfma(mk2(Av.i, Av.i), Tre, pkmul(Ar, Tim));
  }

#define GATE(MASK, ROW, G)                                                  \
  gate9<MASK, ROW>(R, I, rl(c0, G), rl(c1, G), rl(c2, G), rl(c3, G),        \
                   buf, t, lane, wq)

  GATE(0xC00, 0x400, 0);    // w=0   WAVE + l5        (LDS exchange)
  GATE(0x200, 0xE00, 1);    // w=1   lane 0x01        (DPP)
  GATE(0x100, 0xD00, 2);    // w=2   lane 0x02        (DPP)
  GATE(0x080, 0xC80, 3);    // w=3   lane 0x04        (DPP x2)
  GATE(0x040, 0xC40, 4);    // w=4   lane 0x08        (DPP x2)
  GATE(0x020, 0xC20, 5);    // w=5   lane 0x10        (shfl)
  GATE(0x010, 0xC10, 6);    // w=6   reg 0x10
  GATE(0x008, 0xC08, 7);    // w=7   reg 8
  GATE(0x004, 0xC04, 8);    // w=8   reg 4
  GATE(0x002, 0xC02, 9);    // w=9   reg 2
  GATE(0x001, 0xC01, 10);   // w=10  reg 1 (half-swap)
  GATE(0xBFF, 0xC00, 11);   // w=11  lane 0x3F (shfl 0x30 + mirror) + reg 0x1F
#undef GATE

  constexpr int MROWS[12] = {0xFFF, 0xA00, 0x700, 0xB80, 0x7C0, 0xBE0,
                             0x7F0, 0xBF8, 0x7FC, 0xBFE, 0x7FF, 0xBFF};
  const f2 Spp = mk2(1.f, 1.f),  Smm = mk2(-1.f, -1.f);
  const f2 Spm = mk2(1.f, -1.f), Smp = mk2(-1.f, 1.f);
  f2 acc2[12];
#pragma unroll
  for (int w = 0; w < 12; ++w) acc2[w] = mk2(0.f, 0.f);
#pragma unroll
  for (int j = 0; j < 16; ++j) {
    const f2 pr2 = pkfma(I[j], I[j], pkmul(R[j], R[j]));
#pragma unroll
    for (int w = 0; w < 12; ++w) {
      const int sl = parity12(MROWS[w] & (2 * j));
      const int sh = sl ^ parity12(MROWS[w] & 3);
      const f2 S = sl ? (sh ? Smm : Smp) : (sh ? Spm : Spp);
      acc2[w] = pkfma(S, pr2, acc2[w]);
    }
  }
  __syncthreads();                           // gate-0 buf reads long done
  float* sred = (float*)buf;
#pragma unroll
  for (int w = 0; w < 12; ++w) {
    float v = acc2[w].x + acc2[w].y;
    const int sg = (__popc(lanemask_of(MROWS[w]) & lane) ^
                    (wq & ((MROWS[w] >> 10) & 1))) & 1;
    if (sg) v = -v;
    v += lshfl<0x01>(v);
    v += lshfl<0x02>(v);
    v += lshfl<0x04>(v);
    v += lshfl<0x08>(v);
    v += __shfl_xor(v, 16, 64);
    v += __shfl_xor(v, 32, 64);
    if (lane == 0) sred[(t >> 6) * 12 + w] = v;
  }
  __syncthreads();
  if (t < 24) {
    const int rr = t / 12, w = t - rr * 12;
    out[(size_t)(blockIdx.x * 2 + rr) * 12 + w] =
        sred[(rr * 2) * 12 + w] + sred[(rr * 2 + 1) * 12 + w];
  }
}

// ---------------------------------------------------------------------------
extern "C" void kernel_launch(void* const* d_in, const int* in_sizes, int n_in,
                              void* d_out, int out_size, void* d_ws, size_t ws_size,
                              hipStream_t stream) {
  const float* x       = (const float*)d_in[0];
  const float* core0   = (const float*)d_in[1];
  const float* core1   = (const float*)d_in[2];
  const float* tt_bias = (const float*)d_in[3];
  const float* gang    = (const float*)d_in[4];
  float* out = (float*)d_out;
  float* Wt     = (float*)d_ws;                 // 1024*96 floats = 384 KiB
  float* ttout  = (float*)d_ws + 98304;         // 2048*72 floats = 576 KiB

  const int bsz = in_sizes[0] / 1024;  // 2048

  build_w_kernel<<<288, 256, 0, stream>>>(core0, core1, Wt);
  tt_gemm4<<<bsz / 8, 512, 0, stream>>>(x, Wt, tt_bias, ttout);
  vqc_kernel10<<<bsz / 2, 256, 0, stream>>>(x, ttout, gang, out);
}